// Round 1
// baseline (3250.223 us; speedup 1.0000x reference)
//
#include <hip/hip_runtime.h>
#include <math.h>

// Sizes are fixed by the problem: B=2, T=2048, D=1024, F=4096, H=8, DH=128.
#define BSZ 2
#define TLEN 2048
#define DDIM 1024
#define FDIM 4096
#define HHEADS 8
#define DHEAD 128

__device__ __forceinline__ float silu_f(float x) {
    return x / (1.0f + expf(-x));
}

// ---------------- RMSNorm: one block (256 thr) per row of 1024 ----------------
__global__ __launch_bounds__(256) void rmsnorm_k(const float* __restrict__ in,
                                                 float* __restrict__ out) {
    const long row = blockIdx.x;
    const int tid = threadIdx.x;
    const float4 x = *(const float4*)(in + row * DDIM + tid * 4);
    float ss = x.x * x.x + x.y * x.y + x.z * x.z + x.w * x.w;
    ss += __shfl_xor(ss, 1);
    ss += __shfl_xor(ss, 2);
    ss += __shfl_xor(ss, 4);
    ss += __shfl_xor(ss, 8);
    ss += __shfl_xor(ss, 16);
    ss += __shfl_xor(ss, 32);
    __shared__ float wsum[4];
    if ((tid & 63) == 0) wsum[tid >> 6] = ss;
    __syncthreads();
    const float tot = wsum[0] + wsum[1] + wsum[2] + wsum[3];
    const float sc = rsqrtf(tot * (1.0f / (float)DDIM) + 1e-6f);
    float4 y;
    y.x = x.x * sc; y.y = x.y * sc; y.z = x.z * sc; y.w = x.w * sc;
    *(float4*)(out + row * DDIM + tid * 4) = y;
}

// ---------------- fp32 GEMM: C[M,N] = A[M,K] @ B[K,N] (+resid) ----------------
// BM=BN=128, BK=16, 256 threads, 8x8 micro-tile.
template <bool ADD>
__global__ __launch_bounds__(256) void gemm_f32(const float* __restrict__ A,
                                                const float* __restrict__ Bm,
                                                const float* __restrict__ resid,
                                                float* __restrict__ C,
                                                int M, int N, int K) {
    __shared__ float As[16][128];
    __shared__ float Bs[16][128];
    const int tid = threadIdx.x;
    const int m0 = blockIdx.y * 128;
    const int n0 = blockIdx.x * 128;
    const int tx = tid & 15;
    const int ty = tid >> 4;
    const int arow = tid >> 1;
    const int acol = (tid & 1) * 8;
    const int brow = tid >> 4;
    const int bcol = (tid & 15) * 8;
    const float* Ag = A + (long)(m0 + arow) * K + acol;
    const float* Bg = Bm + (long)brow * N + n0 + bcol;
    float acc[8][8];
#pragma unroll
    for (int i = 0; i < 8; ++i)
#pragma unroll
        for (int j = 0; j < 8; ++j) acc[i][j] = 0.0f;

    for (int k0 = 0; k0 < K; k0 += 16) {
        const float4 a0 = *(const float4*)(Ag);
        const float4 a1 = *(const float4*)(Ag + 4);
        const float4 b0 = *(const float4*)(Bg);
        const float4 b1 = *(const float4*)(Bg + 4);
        __syncthreads();
        As[acol + 0][arow] = a0.x;
        As[acol + 1][arow] = a0.y;
        As[acol + 2][arow] = a0.z;
        As[acol + 3][arow] = a0.w;
        As[acol + 4][arow] = a1.x;
        As[acol + 5][arow] = a1.y;
        As[acol + 6][arow] = a1.z;
        As[acol + 7][arow] = a1.w;
        *(float4*)&Bs[brow][bcol] = b0;
        *(float4*)&Bs[brow][bcol + 4] = b1;
        __syncthreads();
#pragma unroll
        for (int kk = 0; kk < 16; ++kk) {
            float av[8], bv[8];
            *(float4*)&av[0] = *(const float4*)&As[kk][ty * 8];
            *(float4*)&av[4] = *(const float4*)&As[kk][ty * 8 + 4];
            *(float4*)&bv[0] = *(const float4*)&Bs[kk][tx * 8];
            *(float4*)&bv[4] = *(const float4*)&Bs[kk][tx * 8 + 4];
#pragma unroll
            for (int i = 0; i < 8; ++i)
#pragma unroll
                for (int j = 0; j < 8; ++j)
                    acc[i][j] = fmaf(av[i], bv[j], acc[i][j]);
        }
        Ag += 16;
        Bg += (long)16 * N;
    }
#pragma unroll
    for (int i = 0; i < 8; ++i) {
        const long row = m0 + ty * 8 + i;
        float* Cp = C + row * (long)N + n0 + tx * 8;
        const float* Rp = resid + row * (long)N + n0 + tx * 8;
#pragma unroll
        for (int j = 0; j < 8; j += 4) {
            float4 val;
            val.x = acc[i][j + 0];
            val.y = acc[i][j + 1];
            val.z = acc[i][j + 2];
            val.w = acc[i][j + 3];
            if (ADD) {
                const float4 r = *(const float4*)(Rp + j);
                val.x += r.x; val.y += r.y; val.z += r.z; val.w += r.w;
            }
            *(float4*)(Cp + j) = val;
        }
    }
}

// ------------- dual-B GEMM for SwiGLU: H = silu(A@Wg) * (A@Wu) -------------
// BM=128, BN=64, BK=16, 256 threads, 8x4 micro-tile x 2 accumulators.
__global__ __launch_bounds__(256) void gemm_gateup(const float* __restrict__ A,
                                                   const float* __restrict__ Bg_,
                                                   const float* __restrict__ Bu_,
                                                   float* __restrict__ Hout,
                                                   int M, int N, int K) {
    __shared__ float As[16][128];
    __shared__ float Bgs[16][64];
    __shared__ float Bus[16][64];
    const int tid = threadIdx.x;
    const int m0 = blockIdx.y * 128;
    const int n0 = blockIdx.x * 64;
    const int tx = tid & 15;   // cols tx*4
    const int ty = tid >> 4;   // rows ty*8
    const int arow = tid >> 1;
    const int acol = (tid & 1) * 8;
    const int brow = tid >> 4;          // 0..15
    const int bcol = (tid & 15) * 4;    // 0..60
    const float* Ag = A + (long)(m0 + arow) * K + acol;
    const float* Bgp = Bg_ + (long)brow * N + n0 + bcol;
    const float* Bup = Bu_ + (long)brow * N + n0 + bcol;
    float accg[8][4], accu[8][4];
#pragma unroll
    for (int i = 0; i < 8; ++i)
#pragma unroll
        for (int j = 0; j < 4; ++j) { accg[i][j] = 0.0f; accu[i][j] = 0.0f; }

    for (int k0 = 0; k0 < K; k0 += 16) {
        const float4 a0 = *(const float4*)(Ag);
        const float4 a1 = *(const float4*)(Ag + 4);
        const float4 bg = *(const float4*)(Bgp);
        const float4 bu = *(const float4*)(Bup);
        __syncthreads();
        As[acol + 0][arow] = a0.x;
        As[acol + 1][arow] = a0.y;
        As[acol + 2][arow] = a0.z;
        As[acol + 3][arow] = a0.w;
        As[acol + 4][arow] = a1.x;
        As[acol + 5][arow] = a1.y;
        As[acol + 6][arow] = a1.z;
        As[acol + 7][arow] = a1.w;
        *(float4*)&Bgs[brow][bcol] = bg;
        *(float4*)&Bus[brow][bcol] = bu;
        __syncthreads();
#pragma unroll
        for (int kk = 0; kk < 16; ++kk) {
            float av[8], bgv[4], buv[4];
            *(float4*)&av[0] = *(const float4*)&As[kk][ty * 8];
            *(float4*)&av[4] = *(const float4*)&As[kk][ty * 8 + 4];
            *(float4*)&bgv[0] = *(const float4*)&Bgs[kk][tx * 4];
            *(float4*)&buv[0] = *(const float4*)&Bus[kk][tx * 4];
#pragma unroll
            for (int i = 0; i < 8; ++i)
#pragma unroll
                for (int j = 0; j < 4; ++j) {
                    accg[i][j] = fmaf(av[i], bgv[j], accg[i][j]);
                    accu[i][j] = fmaf(av[i], buv[j], accu[i][j]);
                }
        }
        Ag += 16;
        Bgp += (long)16 * N;
        Bup += (long)16 * N;
    }
#pragma unroll
    for (int i = 0; i < 8; ++i) {
        const long row = m0 + ty * 8 + i;
        float* Hp = Hout + row * (long)N + n0 + tx * 4;
        float4 hv;
        hv.x = silu_f(accg[i][0]) * accu[i][0];
        hv.y = silu_f(accg[i][1]) * accu[i][1];
        hv.z = silu_f(accg[i][2]) * accu[i][2];
        hv.w = silu_f(accg[i][3]) * accu[i][3];
        *(float4*)Hp = hv;
    }
}

// ------- beta/alpha: per (b,t) row, 16 dot-products of length 1024 -------
__global__ __launch_bounds__(64) void ba_kernel(const float* __restrict__ xn,
                                                const float* __restrict__ wb,
                                                const float* __restrict__ wg,
                                                float* __restrict__ beta,
                                                float* __restrict__ alpha) {
    const long row = blockIdx.x;
    const int tid = threadIdx.x;
    const int o = tid >> 2;   // 0..15 output index (0..7 beta, 8..15 alpha)
    const int p = tid & 3;    // partial segment
    const float* w = (o < 8) ? (wb + o) : (wg + (o - 8));
    const float* xr = xn + row * DDIM + p * 256;
    const float* wr = w + (long)(p * 256) * HHEADS;
    float acc = 0.0f;
#pragma unroll 8
    for (int i = 0; i < 256; ++i)
        acc = fmaf(xr[i], wr[(long)i * HHEADS], acc);
    acc += __shfl_xor(acc, 1);
    acc += __shfl_xor(acc, 2);
    if (p == 0) {
        const float val = 1.0f / (1.0f + expf(-acc));
        if (o < 8) beta[row * HHEADS + o] = val;
        else       alpha[row * HHEADS + (o - 8)] = val;
    }
}

// ------- post-projection: silu + per-head l2norm on q,k; silu on v -------
// one wave per (b,t,h) row of 128
__global__ __launch_bounds__(64) void postqkv(float* __restrict__ q,
                                              float* __restrict__ k,
                                              float* __restrict__ v) {
    const long r = blockIdx.x;
    const int tid = threadIdx.x;
    {
        float* qp = q + r * DHEAD + tid * 2;
        float2 xv = *(float2*)qp;
        float y0 = silu_f(xv.x), y1 = silu_f(xv.y);
        float ss = y0 * y0 + y1 * y1;
        ss += __shfl_xor(ss, 1);  ss += __shfl_xor(ss, 2);
        ss += __shfl_xor(ss, 4);  ss += __shfl_xor(ss, 8);
        ss += __shfl_xor(ss, 16); ss += __shfl_xor(ss, 32);
        const float sc = rsqrtf(ss + 1e-6f);
        float2 yv; yv.x = y0 * sc; yv.y = y1 * sc;
        *(float2*)qp = yv;
    }
    {
        float* kp = k + r * DHEAD + tid * 2;
        float2 xv = *(float2*)kp;
        float y0 = silu_f(xv.x), y1 = silu_f(xv.y);
        float ss = y0 * y0 + y1 * y1;
        ss += __shfl_xor(ss, 1);  ss += __shfl_xor(ss, 2);
        ss += __shfl_xor(ss, 4);  ss += __shfl_xor(ss, 8);
        ss += __shfl_xor(ss, 16); ss += __shfl_xor(ss, 32);
        const float sc = rsqrtf(ss + 1e-6f);
        float2 yv; yv.x = y0 * sc; yv.y = y1 * sc;
        *(float2*)kp = yv;
    }
    {
        float* vp = v + r * DHEAD + tid * 2;
        float2 xv = *(float2*)vp;
        float2 yv; yv.x = silu_f(xv.x); yv.y = silu_f(xv.y);
        *(float2*)vp = yv;
    }
}

// ---------------- sequential gated delta-rule scan ----------------
// Columns of S are independent: 64 blocks = 16 (b,h) x 4 column-groups.
// 256 threads = 32 columns x 8 row-segments (16 rows each, in registers).
__global__ __launch_bounds__(256) void deltanet_scan(const float* __restrict__ qb,
                                                     const float* __restrict__ kb,
                                                     const float* __restrict__ vb,
                                                     const float* __restrict__ betab,
                                                     const float* __restrict__ alphab,
                                                     const float* __restrict__ S0,
                                                     float* __restrict__ ob,
                                                     float* __restrict__ Sout) {
    const int bh = blockIdx.x >> 2;      // 0..15
    const int g = blockIdx.x & 3;        // column group
    const int b = bh >> 3, h = bh & 7;
    const int tid = threadIdx.x;
    const int c = tid >> 3;              // 0..31
    const int p = tid & 7;               // 0..7 row segment
    const int col = g * 32 + c;

    float s[16];
    const float* S0p = S0 + ((long)bh * DHEAD + p * 16) * DHEAD + col;
#pragma unroll
    for (int j = 0; j < 16; ++j) s[j] = S0p[j * DHEAD];

    __shared__ float lk[2][128];
    __shared__ float lq[2][128];

    const long tstride = (long)HHEADS * DHEAD;          // 1024
    const long base0 = ((long)b * TLEN) * tstride + (long)h * DHEAD;
    const int d = tid & 127;
    const bool isq = tid >= 128;
    const float* kqsrc = isq ? qb : kb;

    float pk = kqsrc[base0 + d];
    float pv = vb[base0 + col];
    const long sco = ((long)b * TLEN) * HHEADS + h;
    float pbeta = betab[sco];
    float palpha = alphab[sco];

    for (int t = 0; t < TLEN; ++t) {
        const int cur = t & 1;
        if (!isq) lk[cur][d] = pk; else lq[cur][d] = pk;
        const float cv = pv, cb = pbeta, ca = palpha;
        __syncthreads();
        if (t + 1 < TLEN) {
            const long nb = base0 + (long)(t + 1) * tstride;
            pk = kqsrc[nb + d];
            pv = vb[nb + col];
            const long so = sco + (long)(t + 1) * HHEADS;
            pbeta = betab[so];
            palpha = alphab[so];
        }
        float kk_[16], qq_[16];
#pragma unroll
        for (int j = 0; j < 16; j += 4) {
            *(float4*)&kk_[j] = *(const float4*)&lk[cur][p * 16 + j];
            *(float4*)&qq_[j] = *(const float4*)&lq[cur][p * 16 + j];
        }
        // pred = alpha * dot(k, S_old[:,col])
        float pr0 = 0, pr1 = 0, pr2 = 0, pr3 = 0;
#pragma unroll
        for (int j = 0; j < 16; j += 4) {
            pr0 = fmaf(kk_[j + 0], s[j + 0], pr0);
            pr1 = fmaf(kk_[j + 1], s[j + 1], pr1);
            pr2 = fmaf(kk_[j + 2], s[j + 2], pr2);
            pr3 = fmaf(kk_[j + 3], s[j + 3], pr3);
        }
        float pr = (pr0 + pr1) + (pr2 + pr3);
        pr += __shfl_xor(pr, 1);
        pr += __shfl_xor(pr, 2);
        pr += __shfl_xor(pr, 4);
        const float dv = cb * (cv - ca * pr);
        // S_new = alpha*S_old + k (x) dv ; o = dot(q, S_new[:,col])
        float o0 = 0, o1 = 0, o2 = 0, o3 = 0;
#pragma unroll
        for (int j = 0; j < 16; j += 4) {
            s[j + 0] = fmaf(ca, s[j + 0], kk_[j + 0] * dv); o0 = fmaf(qq_[j + 0], s[j + 0], o0);
            s[j + 1] = fmaf(ca, s[j + 1], kk_[j + 1] * dv); o1 = fmaf(qq_[j + 1], s[j + 1], o1);
            s[j + 2] = fmaf(ca, s[j + 2], kk_[j + 2] * dv); o2 = fmaf(qq_[j + 2], s[j + 2], o2);
            s[j + 3] = fmaf(ca, s[j + 3], kk_[j + 3] * dv); o3 = fmaf(qq_[j + 3], s[j + 3], o3);
        }
        float oo = (o0 + o1) + (o2 + o3);
        oo += __shfl_xor(oo, 1);
        oo += __shfl_xor(oo, 2);
        oo += __shfl_xor(oo, 4);
        if (p == 0) ob[base0 + (long)t * tstride + col] = oo;
    }
    float* Sop = Sout + ((long)bh * DHEAD + p * 16) * DHEAD + col;
#pragma unroll
    for (int j = 0; j < 16; ++j) Sop[j * DHEAD] = s[j];
}

extern "C" void kernel_launch(void* const* d_in, const int* in_sizes, int n_in,
                              void* d_out, int out_size, void* d_ws, size_t ws_size,
                              hipStream_t stream) {
    const float* x     = (const float*)d_in[0];
    const float* S0    = (const float*)d_in[1];
    const float* wq    = (const float*)d_in[2];
    const float* wk    = (const float*)d_in[3];
    const float* wv    = (const float*)d_in[4];
    const float* wb    = (const float*)d_in[5];
    const float* wg    = (const float*)d_in[6];
    const float* wo    = (const float*)d_in[7];
    const float* wgate = (const float*)d_in[8];
    const float* wup   = (const float*)d_in[9];
    const float* wdown = (const float*)d_in[10];

    const int M = BSZ * TLEN;  // 4096 token rows

    float* out  = (float*)d_out;                 // x_out [M, D]
    float* Sout = out + (long)M * DDIM;          // final state [2,8,128,128]

    char* w = (char*)d_ws;
    const long MB16 = 1L << 24;                  // 16 MiB
    float* xn    = (float*)(w);                  // [M, D]    (reused as xn2)
    float* qb    = (float*)(w + 1 * MB16);       // [M, D]
    float* kb    = (float*)(w + 2 * MB16);       // [M, D]
    float* vb    = (float*)(w + 3 * MB16);       // [M, D]
    float* obuf  = (float*)(w + 4 * MB16);       // [M, D]
    float* hidden = qb;                          // [M, F] reuses q..o (64 MiB)
    float* beta  = (float*)(w + 5 * MB16);       // [M, H]
    float* alpha = (float*)(w + 5 * MB16 + (1L << 19));

    // 1) xn = rms_norm(x)
    rmsnorm_k<<<M, 256, 0, stream>>>(x, xn);

    // 2) projections
    dim3 gP(DDIM / 128, M / 128);  // (8, 32)
    gemm_f32<false><<<gP, 256, 0, stream>>>(xn, wq, nullptr, qb, M, DDIM, DDIM);
    gemm_f32<false><<<gP, 256, 0, stream>>>(xn, wk, nullptr, kb, M, DDIM, DDIM);
    gemm_f32<false><<<gP, 256, 0, stream>>>(xn, wv, nullptr, vb, M, DDIM, DDIM);
    ba_kernel<<<M, 64, 0, stream>>>(xn, wb, wg, beta, alpha);
    postqkv<<<M * HHEADS, 64, 0, stream>>>(qb, kb, vb);

    // 3) sequential scan -> o, final state
    deltanet_scan<<<64, 256, 0, stream>>>(qb, kb, vb, beta, alpha, S0, obuf, Sout);

    // 4) x1 = x + o @ wo  (stored in d_out)
    gemm_f32<true><<<gP, 256, 0, stream>>>(obuf, wo, x, out, M, DDIM, DDIM);

    // 5) xn2 = rms_norm(x1)
    rmsnorm_k<<<M, 256, 0, stream>>>(out, xn);

    // 6) hidden = silu(xn2 @ w_gate) * (xn2 @ w_up)
    dim3 gGU(FDIM / 64, M / 128);  // (64, 32)
    gemm_gateup<<<gGU, 256, 0, stream>>>(xn, wgate, wup, hidden, M, FDIM, DDIM);

    // 7) x_out = x1 + hidden @ w_down  (in-place read+write of d_out)
    dim3 gDN(DDIM / 128, M / 128);  // (8, 32)
    gemm_f32<true><<<gDN, 256, 0, stream>>>(hidden, wdown, out, out, M, DDIM, FDIM);
}

// Round 2
// 1703.730 us; speedup vs baseline: 1.9077x; 1.9077x over previous
//
#include <hip/hip_runtime.h>
#include <hip/hip_bf16.h>
#include <math.h>

// Sizes fixed by the problem: B=2, T=2048, D=1024, F=4096, H=8, DH=128.
#define BSZ 2
#define TLEN 2048
#define DDIM 1024
#define FDIM 4096
#define HHEADS 8
#define DHEAD 128

typedef __bf16 bf16x8 __attribute__((ext_vector_type(8)));
typedef float f32x4 __attribute__((ext_vector_type(4)));

__device__ __forceinline__ float silu_f(float x) {
    return x / (1.0f + expf(-x));
}

__device__ __forceinline__ void load_lds16(const void* g, void* l) {
    __builtin_amdgcn_global_load_lds(
        (const __attribute__((address_space(1))) void*)g,
        (__attribute__((address_space(3))) void*)l, 16, 0, 0);
}

// ---------------- RMSNorm: one block (256 thr) per row of 1024; bf16 out -----
struct alignas(8) bh4 { __hip_bfloat16 a, b, c, d; };

__global__ __launch_bounds__(256) void rmsnorm_k(const float* __restrict__ in,
                                                 __hip_bfloat16* __restrict__ out) {
    const long row = blockIdx.x;
    const int tid = threadIdx.x;
    const float4 x = *(const float4*)(in + row * DDIM + tid * 4);
    float ss = x.x * x.x + x.y * x.y + x.z * x.z + x.w * x.w;
    ss += __shfl_xor(ss, 1);
    ss += __shfl_xor(ss, 2);
    ss += __shfl_xor(ss, 4);
    ss += __shfl_xor(ss, 8);
    ss += __shfl_xor(ss, 16);
    ss += __shfl_xor(ss, 32);
    __shared__ float wsum[4];
    if ((tid & 63) == 0) wsum[tid >> 6] = ss;
    __syncthreads();
    const float tot = wsum[0] + wsum[1] + wsum[2] + wsum[3];
    const float sc = rsqrtf(tot * (1.0f / (float)DDIM) + 1e-6f);
    bh4 y;
    y.a = __float2bfloat16(x.x * sc);
    y.b = __float2bfloat16(x.y * sc);
    y.c = __float2bfloat16(x.z * sc);
    y.d = __float2bfloat16(x.w * sc);
    *(bh4*)(out + row * DDIM + tid * 4) = y;
}

// ------------- transpose + f32->bf16: W[K,N] -> Wt[N,K] -------------
__global__ __launch_bounds__(256) void transpose_cvt(const float* __restrict__ W,
                                                     __hip_bfloat16* __restrict__ Wt,
                                                     int K, int N) {
    __shared__ float t[32][33];
    const int n0 = blockIdx.x * 32, k0 = blockIdx.y * 32;
    const int tx = threadIdx.x & 31, ty = threadIdx.x >> 5;  // ty 0..7
#pragma unroll
    for (int i = 0; i < 4; ++i)
        t[ty * 4 + i][tx] = W[(long)(k0 + ty * 4 + i) * N + n0 + tx];
    __syncthreads();
#pragma unroll
    for (int i = 0; i < 4; ++i)
        Wt[(long)(n0 + ty * 4 + i) * K + k0 + tx] = __float2bfloat16(t[tx][ty * 4 + i]);
}

// ---------------- bf16 MFMA GEMM: C[M,N] = A[M,K] @ Bt[N,K]^T (+resid) -------
// m97 structure: BM=BN=128, BK=32, 4 waves, 4x4 16x16x32 fragments per wave.
// MODE 0: C=acc (f32). MODE 1: C=acc+resid (f32).
template <int MODE>
__global__ __launch_bounds__(256) void gemm_bf16(const __hip_bfloat16* __restrict__ A,
                                                 const __hip_bfloat16* __restrict__ Bt,
                                                 const float* __restrict__ resid,
                                                 float* __restrict__ Cf,
                                                 int M, int N, int K) {
    __shared__ __align__(16) short As[128 * 32];
    __shared__ __align__(16) short Bs[128 * 32];
    const int tid = threadIdx.x;
    const int w = tid >> 6, l = tid & 63;
    const int m0 = blockIdx.y * 128, n0 = blockIdx.x * 128;
    // staging: thread covers LDS bytes w*1024 + l*16 (+ j*4096)
    const int srow = (w << 4) + (l >> 2);   // + j*64
    const int skcol = (l & 3) * 8;
    // fragment indices
    const int wr = w >> 1, wc = w & 1;
    const int fr = l & 15;
    const int fkB = (l >> 4) * 16;          // k byte offset within 64B row

    f32x4 acc[4][4];
#pragma unroll
    for (int m = 0; m < 4; ++m)
#pragma unroll
        for (int n = 0; n < 4; ++n) acc[m][n] = (f32x4)0.0f;

    const __hip_bfloat16* Abase = A + (long)m0 * K + skcol;
    const __hip_bfloat16* Bbase = Bt + (long)n0 * K + skcol;

    for (int k0 = 0; k0 < K; k0 += 32) {
#pragma unroll
        for (int j = 0; j < 2; ++j) {
            const int row = srow + j * 64;
            load_lds16(Abase + (long)row * K + k0, (char*)As + w * 1024 + j * 4096);
            load_lds16(Bbase + (long)row * K + k0, (char*)Bs + w * 1024 + j * 4096);
        }
        __syncthreads();
        bf16x8 av[4], bv[4];
#pragma unroll
        for (int m = 0; m < 4; ++m) {
            av[m] = *(const bf16x8*)((char*)As + (wr * 64 + m * 16 + fr) * 64 + fkB);
            bv[m] = *(const bf16x8*)((char*)Bs + (wc * 64 + m * 16 + fr) * 64 + fkB);
        }
#pragma unroll
        for (int m = 0; m < 4; ++m)
#pragma unroll
            for (int n = 0; n < 4; ++n)
                acc[m][n] = __builtin_amdgcn_mfma_f32_16x16x32_bf16(av[m], bv[n], acc[m][n], 0, 0, 0);
        __syncthreads();
    }

    const int r0 = (l >> 4) * 4;
    const int cc = l & 15;
#pragma unroll
    for (int m = 0; m < 4; ++m) {
#pragma unroll
        for (int r = 0; r < 4; ++r) {
            const long row = m0 + wr * 64 + m * 16 + r0 + r;
            float* cp = Cf + row * N + n0 + wc * 64 + cc;
            const float* rp = resid + row * N + n0 + wc * 64 + cc;
#pragma unroll
            for (int n = 0; n < 4; ++n) {
                float v = acc[m][n][r];
                if (MODE == 1) v += rp[n * 16];
                cp[n * 16] = v;
            }
        }
    }
}

// ---- dual-B MFMA GEMM for SwiGLU: H = bf16( silu(A@Wg^T) * (A@Wu^T) ) ------
__global__ __launch_bounds__(256) void gemm_gateup_bf16(const __hip_bfloat16* __restrict__ A,
                                                        const __hip_bfloat16* __restrict__ Bg,
                                                        const __hip_bfloat16* __restrict__ Bu,
                                                        __hip_bfloat16* __restrict__ Hb,
                                                        int M, int N, int K) {
    __shared__ __align__(16) short As[128 * 32];
    __shared__ __align__(16) short Bgs[128 * 32];
    __shared__ __align__(16) short Bus[128 * 32];
    const int tid = threadIdx.x;
    const int w = tid >> 6, l = tid & 63;
    const int m0 = blockIdx.y * 128, n0 = blockIdx.x * 128;
    const int srow = (w << 4) + (l >> 2);
    const int skcol = (l & 3) * 8;
    const int wr = w >> 1, wc = w & 1;
    const int fr = l & 15;
    const int fkB = (l >> 4) * 16;

    f32x4 accg[4][4], accu[4][4];
#pragma unroll
    for (int m = 0; m < 4; ++m)
#pragma unroll
        for (int n = 0; n < 4; ++n) { accg[m][n] = (f32x4)0.0f; accu[m][n] = (f32x4)0.0f; }

    const __hip_bfloat16* Abase = A + (long)m0 * K + skcol;
    const __hip_bfloat16* Bgb = Bg + (long)n0 * K + skcol;
    const __hip_bfloat16* Bub = Bu + (long)n0 * K + skcol;

    for (int k0 = 0; k0 < K; k0 += 32) {
#pragma unroll
        for (int j = 0; j < 2; ++j) {
            const int row = srow + j * 64;
            load_lds16(Abase + (long)row * K + k0, (char*)As + w * 1024 + j * 4096);
            load_lds16(Bgb + (long)row * K + k0, (char*)Bgs + w * 1024 + j * 4096);
            load_lds16(Bub + (long)row * K + k0, (char*)Bus + w * 1024 + j * 4096);
        }
        __syncthreads();
        bf16x8 av[4], bgv[4], buv[4];
#pragma unroll
        for (int m = 0; m < 4; ++m) {
            av[m] = *(const bf16x8*)((char*)As + (wr * 64 + m * 16 + fr) * 64 + fkB);
            bgv[m] = *(const bf16x8*)((char*)Bgs + (wc * 64 + m * 16 + fr) * 64 + fkB);
            buv[m] = *(const bf16x8*)((char*)Bus + (wc * 64 + m * 16 + fr) * 64 + fkB);
        }
#pragma unroll
        for (int m = 0; m < 4; ++m)
#pragma unroll
            for (int n = 0; n < 4; ++n) {
                accg[m][n] = __builtin_amdgcn_mfma_f32_16x16x32_bf16(av[m], bgv[n], accg[m][n], 0, 0, 0);
                accu[m][n] = __builtin_amdgcn_mfma_f32_16x16x32_bf16(av[m], buv[n], accu[m][n], 0, 0, 0);
            }
        __syncthreads();
    }

    const int r0 = (l >> 4) * 4;
    const int cc = l & 15;
#pragma unroll
    for (int m = 0; m < 4; ++m) {
#pragma unroll
        for (int r = 0; r < 4; ++r) {
            const long row = m0 + wr * 64 + m * 16 + r0 + r;
            __hip_bfloat16* hp = Hb + row * N + n0 + wc * 64 + cc;
#pragma unroll
            for (int n = 0; n < 4; ++n)
                hp[n * 16] = __float2bfloat16(silu_f(accg[m][n][r]) * accu[m][n][r]);
        }
    }
}

// ------- beta/alpha: inline rmsnorm (scale folds out of the dot) -------
__global__ __launch_bounds__(64) void ba_kernel(const float* __restrict__ x,
                                                const float* __restrict__ wb,
                                                const float* __restrict__ wg,
                                                float* __restrict__ beta,
                                                float* __restrict__ alpha) {
    const long row = blockIdx.x;
    const int tid = threadIdx.x;
    const int o = tid >> 2;   // 0..15 output index (0..7 beta, 8..15 alpha)
    const int p = tid & 3;    // partial segment
    const float* w = (o < 8) ? (wb + o) : (wg + (o - 8));
    const float* xr = x + row * DDIM + p * 256;
    const float* wr = w + (long)(p * 256) * HHEADS;
    float acc = 0.0f, ss = 0.0f;
#pragma unroll 8
    for (int i = 0; i < 256; ++i) {
        const float xv = xr[i];
        ss = fmaf(xv, xv, ss);
        acc = fmaf(xv, wr[(long)i * HHEADS], acc);
    }
    acc += __shfl_xor(acc, 1);
    acc += __shfl_xor(acc, 2);
    ss += __shfl_xor(ss, 1);
    ss += __shfl_xor(ss, 2);
    if (p == 0) {
        const float sc = rsqrtf(ss * (1.0f / (float)DDIM) + 1e-6f);
        const float val = 1.0f / (1.0f + expf(-acc * sc));
        if (o < 8) beta[row * HHEADS + o] = val;
        else       alpha[row * HHEADS + (o - 8)] = val;
    }
}

// ------- post-projection: silu + per-head l2norm on q,k; silu on v -------
__global__ __launch_bounds__(64) void postqkv(float* __restrict__ q,
                                              float* __restrict__ k,
                                              float* __restrict__ v) {
    const long r = blockIdx.x;
    const int tid = threadIdx.x;
    {
        float* qp = q + r * DHEAD + tid * 2;
        float2 xv = *(float2*)qp;
        float y0 = silu_f(xv.x), y1 = silu_f(xv.y);
        float ss = y0 * y0 + y1 * y1;
        ss += __shfl_xor(ss, 1);  ss += __shfl_xor(ss, 2);
        ss += __shfl_xor(ss, 4);  ss += __shfl_xor(ss, 8);
        ss += __shfl_xor(ss, 16); ss += __shfl_xor(ss, 32);
        const float sc = rsqrtf(ss + 1e-6f);
        float2 yv; yv.x = y0 * sc; yv.y = y1 * sc;
        *(float2*)qp = yv;
    }
    {
        float* kp = k + r * DHEAD + tid * 2;
        float2 xv = *(float2*)kp;
        float y0 = silu_f(xv.x), y1 = silu_f(xv.y);
        float ss = y0 * y0 + y1 * y1;
        ss += __shfl_xor(ss, 1);  ss += __shfl_xor(ss, 2);
        ss += __shfl_xor(ss, 4);  ss += __shfl_xor(ss, 8);
        ss += __shfl_xor(ss, 16); ss += __shfl_xor(ss, 32);
        const float sc = rsqrtf(ss + 1e-6f);
        float2 yv; yv.x = y0 * sc; yv.y = y1 * sc;
        *(float2*)kp = yv;
    }
    {
        float* vp = v + r * DHEAD + tid * 2;
        float2 xv = *(float2*)vp;
        float2 yv; yv.x = silu_f(xv.x); yv.y = silu_f(xv.y);
        *(float2*)vp = yv;
    }
}

// ---------------- sequential gated delta-rule scan (bf16 o out) --------------
__global__ __launch_bounds__(256) void deltanet_scan(const float* __restrict__ qb,
                                                     const float* __restrict__ kb,
                                                     const float* __restrict__ vb,
                                                     const float* __restrict__ betab,
                                                     const float* __restrict__ alphab,
                                                     const float* __restrict__ S0,
                                                     __hip_bfloat16* __restrict__ ob,
                                                     float* __restrict__ Sout) {
    const int bh = blockIdx.x >> 2;      // 0..15
    const int g = blockIdx.x & 3;        // column group
    const int b = bh >> 3, h = bh & 7;
    const int tid = threadIdx.x;
    const int c = tid >> 3;              // 0..31
    const int p = tid & 7;               // 0..7 row segment
    const int col = g * 32 + c;

    float s[16];
    const float* S0p = S0 + ((long)bh * DHEAD + p * 16) * DHEAD + col;
#pragma unroll
    for (int j = 0; j < 16; ++j) s[j] = S0p[j * DHEAD];

    __shared__ float lk[2][128];
    __shared__ float lq[2][128];

    const long tstride = (long)HHEADS * DHEAD;          // 1024
    const long base0 = ((long)b * TLEN) * tstride + (long)h * DHEAD;
    const int d = tid & 127;
    const bool isq = tid >= 128;
    const float* kqsrc = isq ? qb : kb;

    float pk = kqsrc[base0 + d];
    float pv = vb[base0 + col];
    const long sco = ((long)b * TLEN) * HHEADS + h;
    float pbeta = betab[sco];
    float palpha = alphab[sco];

    for (int t = 0; t < TLEN; ++t) {
        const int cur = t & 1;
        if (!isq) lk[cur][d] = pk; else lq[cur][d] = pk;
        const float cv = pv, cb = pbeta, ca = palpha;
        __syncthreads();
        if (t + 1 < TLEN) {
            const long nb = base0 + (long)(t + 1) * tstride;
            pk = kqsrc[nb + d];
            pv = vb[nb + col];
            const long so = sco + (long)(t + 1) * HHEADS;
            pbeta = betab[so];
            palpha = alphab[so];
        }
        float kk_[16], qq_[16];
#pragma unroll
        for (int j = 0; j < 16; j += 4) {
            *(float4*)&kk_[j] = *(const float4*)&lk[cur][p * 16 + j];
            *(float4*)&qq_[j] = *(const float4*)&lq[cur][p * 16 + j];
        }
        float pr0 = 0, pr1 = 0, pr2 = 0, pr3 = 0;
#pragma unroll
        for (int j = 0; j < 16; j += 4) {
            pr0 = fmaf(kk_[j + 0], s[j + 0], pr0);
            pr1 = fmaf(kk_[j + 1], s[j + 1], pr1);
            pr2 = fmaf(kk_[j + 2], s[j + 2], pr2);
            pr3 = fmaf(kk_[j + 3], s[j + 3], pr3);
        }
        float pr = (pr0 + pr1) + (pr2 + pr3);
        pr += __shfl_xor(pr, 1);
        pr += __shfl_xor(pr, 2);
        pr += __shfl_xor(pr, 4);
        const float dv = cb * (cv - ca * pr);
        float o0 = 0, o1 = 0, o2 = 0, o3 = 0;
#pragma unroll
        for (int j = 0; j < 16; j += 4) {
            s[j + 0] = fmaf(ca, s[j + 0], kk_[j + 0] * dv); o0 = fmaf(qq_[j + 0], s[j + 0], o0);
            s[j + 1] = fmaf(ca, s[j + 1], kk_[j + 1] * dv); o1 = fmaf(qq_[j + 1], s[j + 1], o1);
            s[j + 2] = fmaf(ca, s[j + 2], kk_[j + 2] * dv); o2 = fmaf(qq_[j + 2], s[j + 2], o2);
            s[j + 3] = fmaf(ca, s[j + 3], kk_[j + 3] * dv); o3 = fmaf(qq_[j + 3], s[j + 3], o3);
        }
        float oo = (o0 + o1) + (o2 + o3);
        oo += __shfl_xor(oo, 1);
        oo += __shfl_xor(oo, 2);
        oo += __shfl_xor(oo, 4);
        if (p == 0) ob[base0 + (long)t * tstride + col] = __float2bfloat16(oo);
    }
    float* Sop = Sout + ((long)bh * DHEAD + p * 16) * DHEAD + col;
#pragma unroll
    for (int j = 0; j < 16; ++j) Sop[j * DHEAD] = s[j];
}

extern "C" void kernel_launch(void* const* d_in, const int* in_sizes, int n_in,
                              void* d_out, int out_size, void* d_ws, size_t ws_size,
                              hipStream_t stream) {
    const float* x     = (const float*)d_in[0];
    const float* S0    = (const float*)d_in[1];
    const float* wq    = (const float*)d_in[2];
    const float* wk    = (const float*)d_in[3];
    const float* wv    = (const float*)d_in[4];
    const float* wb    = (const float*)d_in[5];
    const float* wg    = (const float*)d_in[6];
    const float* wo    = (const float*)d_in[7];
    const float* wgate = (const float*)d_in[8];
    const float* wup   = (const float*)d_in[9];
    const float* wdown = (const float*)d_in[10];

    const int M = BSZ * TLEN;  // 4096 token rows

    float* out  = (float*)d_out;                 // x_out [M, D]
    float* Sout = out + (long)M * DDIM;          // final state [2,8,128,128]

    char* w = (char*)d_ws;
    const size_t MB = 1u << 20;
    // Workspace layout (live ranges annotated; total 81 MB):
    float*          qb    = (float*)(w + 0 * MB);            // [M,D] f32 (GEMM1 -> scan)
    __hip_bfloat16* xnb   = (__hip_bfloat16*)(w + 16 * MB);  // [M,D] bf16 (rms1 -> GEMM1-3)
    float*          kb    = (float*)(w + 24 * MB);           // [M,D] f32
    float*          vb    = (float*)(w + 40 * MB);           // [M,D] f32
    __hip_bfloat16* obufb = (__hip_bfloat16*)(w + 16 * MB);  // [M,D] bf16 (scan -> GEMM4; xnb dead)
    __hip_bfloat16* xn2b  = (__hip_bfloat16*)(w + 40 * MB);  // [M,D] bf16 (rms2 -> gateup; vb dead)
    __hip_bfloat16* Hb    = (__hip_bfloat16*)(w + 0 * MB);   // [M,F] bf16 (gateup -> GEMM7; q/o/k dead)
    float*          beta  = (float*)(w + 56 * MB);           // [M,H]
    float*          alpha = (float*)(w + 56 * MB + 131072);  // [M,H]
    __hip_bfloat16* wgt   = (__hip_bfloat16*)(w + 57 * MB);  // [F,D] bf16
    __hip_bfloat16* wut   = (__hip_bfloat16*)(w + 65 * MB);  // [F,D] bf16
    __hip_bfloat16* wqt   = (__hip_bfloat16*)(w + 73 * MB);  // [D,D] bf16
    __hip_bfloat16* wkt   = (__hip_bfloat16*)(w + 75 * MB);
    __hip_bfloat16* wvt   = (__hip_bfloat16*)(w + 77 * MB);
    __hip_bfloat16* wot   = (__hip_bfloat16*)(w + 79 * MB);
    __hip_bfloat16* wdt   = (__hip_bfloat16*)(w + 73 * MB);  // [D,F] bf16 (after GEMM4; wq..wo dead)

    // 0) weight transpose+convert (W[K,N] -> Wt[N,K] bf16)
    transpose_cvt<<<dim3(DDIM / 32, DDIM / 32), 256, 0, stream>>>(wq, wqt, DDIM, DDIM);
    transpose_cvt<<<dim3(DDIM / 32, DDIM / 32), 256, 0, stream>>>(wk, wkt, DDIM, DDIM);
    transpose_cvt<<<dim3(DDIM / 32, DDIM / 32), 256, 0, stream>>>(wv, wvt, DDIM, DDIM);
    transpose_cvt<<<dim3(DDIM / 32, DDIM / 32), 256, 0, stream>>>(wo, wot, DDIM, DDIM);
    transpose_cvt<<<dim3(FDIM / 32, DDIM / 32), 256, 0, stream>>>(wgate, wgt, DDIM, FDIM);
    transpose_cvt<<<dim3(FDIM / 32, DDIM / 32), 256, 0, stream>>>(wup, wut, DDIM, FDIM);

    // 1) xn = rms_norm(x) -> bf16 ; beta/alpha from raw x (inline norm)
    rmsnorm_k<<<M, 256, 0, stream>>>(x, xnb);
    ba_kernel<<<M, 64, 0, stream>>>(x, wb, wg, beta, alpha);

    // 2) q/k/v projections (bf16 MFMA, f32 out)
    dim3 gP(DDIM / 128, M / 128);  // (8, 32)
    gemm_bf16<0><<<gP, 256, 0, stream>>>(xnb, wqt, nullptr, qb, M, DDIM, DDIM);
    gemm_bf16<0><<<gP, 256, 0, stream>>>(xnb, wkt, nullptr, kb, M, DDIM, DDIM);
    gemm_bf16<0><<<gP, 256, 0, stream>>>(xnb, wvt, nullptr, vb, M, DDIM, DDIM);
    postqkv<<<M * HHEADS, 64, 0, stream>>>(qb, kb, vb);

    // 3) sequential scan -> o (bf16), final state (f32)
    deltanet_scan<<<64, 256, 0, stream>>>(qb, kb, vb, beta, alpha, S0, obufb, Sout);

    // 4) x1 = x + o @ wo
    gemm_bf16<1><<<gP, 256, 0, stream>>>(obufb, wot, x, out, M, DDIM, DDIM);

    // 4b) transpose w_down into the (now dead) wq..wo slot
    transpose_cvt<<<dim3(DDIM / 32, FDIM / 32), 256, 0, stream>>>(wdown, wdt, FDIM, DDIM);

    // 5) xn2 = rms_norm(x1) -> bf16
    rmsnorm_k<<<M, 256, 0, stream>>>(out, xn2b);

    // 6) H = silu(xn2 @ w_gate) * (xn2 @ w_up) -> bf16
    dim3 gGU(FDIM / 128, M / 128);  // (32, 32)
    gemm_gateup_bf16<<<gGU, 256, 0, stream>>>(xn2b, wgt, wut, Hb, M, FDIM, DDIM);

    // 7) x_out = x1 + H @ w_down
    dim3 gDN(DDIM / 128, M / 128);  // (8, 32)
    gemm_bf16<1><<<gDN, 256, 0, stream>>>(Hb, wdt, out, out, M, DDIM, FDIM);
}

// Round 4
// 854.899 us; speedup vs baseline: 3.8019x; 1.9929x over previous
//
#include <hip/hip_runtime.h>
#include <hip/hip_bf16.h>
#include <math.h>

// Sizes fixed by the problem: B=2, T=2048, D=1024, F=4096, H=8, DH=128.
#define BSZ 2
#define TLEN 2048
#define DDIM 1024
#define FDIM 4096
#define HHEADS 8
#define DHEAD 128
#define NC 32   // chunks per sequence
#define CS 64   // chunk size (CS*NC == TLEN)

typedef __bf16 bf16x8 __attribute__((ext_vector_type(8)));
typedef float f32x4 __attribute__((ext_vector_type(4)));

__device__ __forceinline__ float silu_f(float x) {
    return x / (1.0f + expf(-x));
}

__device__ __forceinline__ void load_lds16(const void* g, void* l) {
    __builtin_amdgcn_global_load_lds(
        (const __attribute__((address_space(1))) void*)g,
        (__attribute__((address_space(3))) void*)l, 16, 0, 0);
}

__device__ __forceinline__ unsigned short bf16_bits(float f) {
    __hip_bfloat16 h = __float2bfloat16(f);
    return *reinterpret_cast<unsigned short*>(&h);
}

__device__ __forceinline__ float bfbits2f(unsigned short u) {
    union { unsigned int i; float f; } c;
    c.i = ((unsigned int)u) << 16;
    return c.f;
}

__device__ __forceinline__ uint4 pack8_bf16(const float* f) {
    union { unsigned short u[8]; uint4 v; } r;
#pragma unroll
    for (int i = 0; i < 8; ++i) r.u[i] = bf16_bits(f[i]);
    return r.v;
}

// ---------------- RMSNorm: one block (256 thr) per row of 1024; bf16 out -----
struct alignas(8) bh4 { __hip_bfloat16 a, b, c, d; };

__global__ __launch_bounds__(256) void rmsnorm_k(const float* __restrict__ in,
                                                 __hip_bfloat16* __restrict__ out) {
    const long row = blockIdx.x;
    const int tid = threadIdx.x;
    const float4 x = *(const float4*)(in + row * DDIM + tid * 4);
    float ss = x.x * x.x + x.y * x.y + x.z * x.z + x.w * x.w;
    ss += __shfl_xor(ss, 1);
    ss += __shfl_xor(ss, 2);
    ss += __shfl_xor(ss, 4);
    ss += __shfl_xor(ss, 8);
    ss += __shfl_xor(ss, 16);
    ss += __shfl_xor(ss, 32);
    __shared__ float wsum[4];
    if ((tid & 63) == 0) wsum[tid >> 6] = ss;
    __syncthreads();
    const float tot = wsum[0] + wsum[1] + wsum[2] + wsum[3];
    const float sc = rsqrtf(tot * (1.0f / (float)DDIM) + 1e-6f);
    bh4 y;
    y.a = __float2bfloat16(x.x * sc);
    y.b = __float2bfloat16(x.y * sc);
    y.c = __float2bfloat16(x.z * sc);
    y.d = __float2bfloat16(x.w * sc);
    *(bh4*)(out + row * DDIM + tid * 4) = y;
}

// ------------- transpose + f32->bf16: W[K,N] -> Wt[N,K] -------------
__global__ __launch_bounds__(256) void transpose_cvt(const float* __restrict__ W,
                                                     __hip_bfloat16* __restrict__ Wt,
                                                     int K, int N) {
    __shared__ float t[32][33];
    const int n0 = blockIdx.x * 32, k0 = blockIdx.y * 32;
    const int tx = threadIdx.x & 31, ty = threadIdx.x >> 5;  // ty 0..7
#pragma unroll
    for (int i = 0; i < 4; ++i)
        t[ty * 4 + i][tx] = W[(long)(k0 + ty * 4 + i) * N + n0 + tx];
    __syncthreads();
#pragma unroll
    for (int i = 0; i < 4; ++i)
        Wt[(long)(n0 + ty * 4 + i) * K + k0 + tx] = __float2bfloat16(t[tx][ty * 4 + i]);
}

// ---------------- bf16 MFMA GEMM: C[M,N] = A[M,K] @ Bt[N,K]^T -------
// MODE 0: f32 out. MODE 1: f32 out + f32 resid. MODE 2: bf16 out.
template <int MODE>
__global__ __launch_bounds__(256) void gemm_bf16(const __hip_bfloat16* __restrict__ A,
                                                 const __hip_bfloat16* __restrict__ Bt,
                                                 const float* __restrict__ resid,
                                                 void* __restrict__ Cout,
                                                 int M, int N, int K) {
    __shared__ __align__(16) short As[128 * 32];
    __shared__ __align__(16) short Bs[128 * 32];
    const int tid = threadIdx.x;
    const int w = tid >> 6, l = tid & 63;
    const int m0 = blockIdx.y * 128, n0 = blockIdx.x * 128;
    const int srow = (w << 4) + (l >> 2);
    const int skcol = (l & 3) * 8;
    const int wr = w >> 1, wc = w & 1;
    const int fr = l & 15;
    const int fkB = (l >> 4) * 16;

    f32x4 acc[4][4];
#pragma unroll
    for (int m = 0; m < 4; ++m)
#pragma unroll
        for (int n = 0; n < 4; ++n) acc[m][n] = (f32x4)0.0f;

    const __hip_bfloat16* Abase = A + (long)m0 * K + skcol;
    const __hip_bfloat16* Bbase = Bt + (long)n0 * K + skcol;

    for (int k0 = 0; k0 < K; k0 += 32) {
#pragma unroll
        for (int j = 0; j < 2; ++j) {
            const int row = srow + j * 64;
            load_lds16(Abase + (long)row * K + k0, (char*)As + w * 1024 + j * 4096);
            load_lds16(Bbase + (long)row * K + k0, (char*)Bs + w * 1024 + j * 4096);
        }
        __syncthreads();
        bf16x8 av[4], bv[4];
#pragma unroll
        for (int m = 0; m < 4; ++m) {
            av[m] = *(const bf16x8*)((char*)As + (wr * 64 + m * 16 + fr) * 64 + fkB);
            bv[m] = *(const bf16x8*)((char*)Bs + (wc * 64 + m * 16 + fr) * 64 + fkB);
        }
#pragma unroll
        for (int m = 0; m < 4; ++m)
#pragma unroll
            for (int n = 0; n < 4; ++n)
                acc[m][n] = __builtin_amdgcn_mfma_f32_16x16x32_bf16(av[m], bv[n], acc[m][n], 0, 0, 0);
        __syncthreads();
    }

    const int r0 = (l >> 4) * 4;
    const int cc = l & 15;
#pragma unroll
    for (int m = 0; m < 4; ++m) {
#pragma unroll
        for (int r = 0; r < 4; ++r) {
            const long row = m0 + wr * 64 + m * 16 + r0 + r;
            const long colb = n0 + wc * 64 + cc;
            if (MODE == 2) {
                __hip_bfloat16* cb = (__hip_bfloat16*)Cout + row * N + colb;
#pragma unroll
                for (int n = 0; n < 4; ++n)
                    cb[n * 16] = __float2bfloat16(acc[m][n][r]);
            } else {
                float* cp = (float*)Cout + row * N + colb;
                const float* rp = resid + row * N + colb;
#pragma unroll
                for (int n = 0; n < 4; ++n) {
                    float v = acc[m][n][r];
                    if (MODE == 1) v += rp[n * 16];
                    cp[n * 16] = v;
                }
            }
        }
    }
}

// ---- dual-B MFMA GEMM for SwiGLU: H = bf16( silu(A@Wg^T) * (A@Wu^T) ) ------
__global__ __launch_bounds__(256) void gemm_gateup_bf16(const __hip_bfloat16* __restrict__ A,
                                                        const __hip_bfloat16* __restrict__ Bg,
                                                        const __hip_bfloat16* __restrict__ Bu,
                                                        __hip_bfloat16* __restrict__ Hb,
                                                        int M, int N, int K) {
    __shared__ __align__(16) short As[128 * 32];
    __shared__ __align__(16) short Bgs[128 * 32];
    __shared__ __align__(16) short Bus[128 * 32];
    const int tid = threadIdx.x;
    const int w = tid >> 6, l = tid & 63;
    const int m0 = blockIdx.y * 128, n0 = blockIdx.x * 128;
    const int srow = (w << 4) + (l >> 2);
    const int skcol = (l & 3) * 8;
    const int wr = w >> 1, wc = w & 1;
    const int fr = l & 15;
    const int fkB = (l >> 4) * 16;

    f32x4 accg[4][4], accu[4][4];
#pragma unroll
    for (int m = 0; m < 4; ++m)
#pragma unroll
        for (int n = 0; n < 4; ++n) { accg[m][n] = (f32x4)0.0f; accu[m][n] = (f32x4)0.0f; }

    const __hip_bfloat16* Abase = A + (long)m0 * K + skcol;
    const __hip_bfloat16* Bgb = Bg + (long)n0 * K + skcol;
    const __hip_bfloat16* Bub = Bu + (long)n0 * K + skcol;

    for (int k0 = 0; k0 < K; k0 += 32) {
#pragma unroll
        for (int j = 0; j < 2; ++j) {
            const int row = srow + j * 64;
            load_lds16(Abase + (long)row * K + k0, (char*)As + w * 1024 + j * 4096);
            load_lds16(Bgb + (long)row * K + k0, (char*)Bgs + w * 1024 + j * 4096);
            load_lds16(Bub + (long)row * K + k0, (char*)Bus + w * 1024 + j * 4096);
        }
        __syncthreads();
        bf16x8 av[4], bgv[4], buv[4];
#pragma unroll
        for (int m = 0; m < 4; ++m) {
            av[m] = *(const bf16x8*)((char*)As + (wr * 64 + m * 16 + fr) * 64 + fkB);
            bgv[m] = *(const bf16x8*)((char*)Bgs + (wc * 64 + m * 16 + fr) * 64 + fkB);
            buv[m] = *(const bf16x8*)((char*)Bus + (wc * 64 + m * 16 + fr) * 64 + fkB);
        }
#pragma unroll
        for (int m = 0; m < 4; ++m)
#pragma unroll
            for (int n = 0; n < 4; ++n) {
                accg[m][n] = __builtin_amdgcn_mfma_f32_16x16x32_bf16(av[m], bgv[n], accg[m][n], 0, 0, 0);
                accu[m][n] = __builtin_amdgcn_mfma_f32_16x16x32_bf16(av[m], buv[n], accu[m][n], 0, 0, 0);
            }
        __syncthreads();
    }

    const int r0 = (l >> 4) * 4;
    const int cc = l & 15;
#pragma unroll
    for (int m = 0; m < 4; ++m) {
#pragma unroll
        for (int r = 0; r < 4; ++r) {
            const long row = m0 + wr * 64 + m * 16 + r0 + r;
            __hip_bfloat16* hp = Hb + row * N + n0 + wc * 64 + cc;
#pragma unroll
            for (int n = 0; n < 4; ++n)
                hp[n * 16] = __float2bfloat16(silu_f(accg[m][n][r]) * accu[m][n][r]);
        }
    }
}

// ------- beta/alpha: inline rmsnorm (scale folds out of the dot) -------
__global__ __launch_bounds__(64) void ba_kernel(const float* __restrict__ x,
                                                const float* __restrict__ wb,
                                                const float* __restrict__ wg,
                                                float* __restrict__ beta,
                                                float* __restrict__ alpha) {
    const long row = blockIdx.x;
    const int tid = threadIdx.x;
    const int o = tid >> 2;
    const int p = tid & 3;
    const float* w = (o < 8) ? (wb + o) : (wg + (o - 8));
    const float* xr = x + row * DDIM + p * 256;
    const float* wr = w + (long)(p * 256) * HHEADS;
    float acc = 0.0f, ss = 0.0f;
#pragma unroll 8
    for (int i = 0; i < 256; ++i) {
        const float xv = xr[i];
        ss = fmaf(xv, xv, ss);
        acc = fmaf(xv, wr[(long)i * HHEADS], acc);
    }
    acc += __shfl_xor(acc, 1);
    acc += __shfl_xor(acc, 2);
    ss += __shfl_xor(ss, 1);
    ss += __shfl_xor(ss, 2);
    if (p == 0) {
        const float sc = rsqrtf(ss * (1.0f / (float)DDIM) + 1e-6f);
        const float val = 1.0f / (1.0f + expf(-acc * sc));
        if (o < 8) beta[row * HHEADS + o] = val;
        else       alpha[row * HHEADS + (o - 8)] = val;
    }
}

// ------- post-projection (bf16 in-place): silu + l2norm on q,k; silu on v ----
__global__ __launch_bounds__(64) void postqkv(__hip_bfloat16* __restrict__ q,
                                              __hip_bfloat16* __restrict__ k,
                                              __hip_bfloat16* __restrict__ v) {
    const long r = blockIdx.x;
    const int tid = threadIdx.x;
    {
        unsigned int* qp = (unsigned int*)(q + r * DHEAD + tid * 2);
        const unsigned int wbits = *qp;
        float y0 = silu_f(bfbits2f(wbits & 0xffff));
        float y1 = silu_f(bfbits2f(wbits >> 16));
        float ss = y0 * y0 + y1 * y1;
        ss += __shfl_xor(ss, 1);  ss += __shfl_xor(ss, 2);
        ss += __shfl_xor(ss, 4);  ss += __shfl_xor(ss, 8);
        ss += __shfl_xor(ss, 16); ss += __shfl_xor(ss, 32);
        const float sc = rsqrtf(ss + 1e-6f);
        *qp = (unsigned int)bf16_bits(y0 * sc) | ((unsigned int)bf16_bits(y1 * sc) << 16);
    }
    {
        unsigned int* kp = (unsigned int*)(k + r * DHEAD + tid * 2);
        const unsigned int wbits = *kp;
        float y0 = silu_f(bfbits2f(wbits & 0xffff));
        float y1 = silu_f(bfbits2f(wbits >> 16));
        float ss = y0 * y0 + y1 * y1;
        ss += __shfl_xor(ss, 1);  ss += __shfl_xor(ss, 2);
        ss += __shfl_xor(ss, 4);  ss += __shfl_xor(ss, 8);
        ss += __shfl_xor(ss, 16); ss += __shfl_xor(ss, 32);
        const float sc = rsqrtf(ss + 1e-6f);
        *kp = (unsigned int)bf16_bits(y0 * sc) | ((unsigned int)bf16_bits(y1 * sc) << 16);
    }
    {
        unsigned int* vp = (unsigned int*)(v + r * DHEAD + tid * 2);
        const unsigned int wbits = *vp;
        *vp = (unsigned int)bf16_bits(silu_f(bfbits2f(wbits & 0xffff)))
            | ((unsigned int)bf16_bits(silu_f(bfbits2f(wbits >> 16))) << 16);
    }
}

// ============ Chunked gated delta rule (log-space decay) ============
// G_t = sum_{s<=t} log(a_s) within chunk; ratio(t,s)=exp(G_t-G_s)<=1 for s<=t.
//   (I+W) dv = u,  W[t,s] = b_t exp(G_t-G_s)(k_t.k_s)  (s<t)
//   u_t = b_t v_t - b_t exp(G_t) (S0^T k_t)
//   o_t = exp(G_t) (S0^T q_t) + sum_{s<=t} exp(G_t-G_s)(q_t.k_s) dv_s
//   S_end = exp(G_63) S0 + sum_s exp(G_63-G_s) k_s dv_s^T

// --------- Phase A (parallel over bh x chunk): G, Tinv=(I+W)^-1, M, dv0 ------
__global__ __launch_bounds__(256) void chunk_prep(
    const __hip_bfloat16* __restrict__ kb, const __hip_bfloat16* __restrict__ qb,
    const __hip_bfloat16* __restrict__ vb, const float* __restrict__ betab,
    const float* __restrict__ alphab, float* __restrict__ Gcum,
    __hip_bfloat16* __restrict__ Tinv, __hip_bfloat16* __restrict__ dvX,
    __hip_bfloat16* __restrict__ Mmat)
{
    const int bh = blockIdx.x >> 5;
    const int c  = blockIdx.x & 31;
    const int b = bh >> 3, h = bh & 7;
    const int tid = threadIdx.x;

    __shared__ __align__(16) __hip_bfloat16 tA[64][136];   // k chunk
    __shared__ __align__(16) __hip_bfloat16 tB[64][136];   // q chunk, later b*v
    __shared__ __hip_bfloat16 Wl[64][66];
    __shared__ float Ti[64][65];
    __shared__ float sa[64], sb_[64], sG[64];

    const long row0 = (long)b * TLEN + (long)c * CS;
    const long chnk = (long)bh * NC + c;

    if (tid < 64) {
        sa[tid]  = alphab[(row0 + tid) * HHEADS + h];
        sb_[tid] = betab[(row0 + tid) * HHEADS + h];
    }
    // load k,q chunks (bf16 direct copies)
    {
        const int r = tid >> 2;
        const int d0 = (tid & 3) * 32;
        const uint4* kp = (const uint4*)(kb + (row0 + r) * DDIM + h * DHEAD + d0);
        const uint4* qp = (const uint4*)(qb + (row0 + r) * DDIM + h * DHEAD + d0);
#pragma unroll
        for (int i = 0; i < 4; ++i) {
            *(uint4*)&tA[r][d0 + i * 8] = kp[i];
            *(uint4*)&tB[r][d0 + i * 8] = qp[i];
        }
    }
    __syncthreads();
    if (tid == 0) {
        float run = 0.0f;
        for (int t = 0; t < CS; ++t) { run += logf(sa[t]); sG[t] = run; }
    }
    __syncthreads();
    if (tid < 64) Gcum[chnk * CS + tid] = sG[tid];

    // W[t][s] (s<t) and M[t][s] (s<=t)
    {
        const int t = tid >> 2;
        const int s0 = (tid & 3) * 16;
        float accW[16], accM[16];
#pragma unroll
        for (int i = 0; i < 16; ++i) { accW[i] = 0.0f; accM[i] = 0.0f; }
        for (int d = 0; d < DHEAD; ++d) {
            const float at = __bfloat162float(tA[t][d]);
            const float bt = __bfloat162float(tB[t][d]);
#pragma unroll
            for (int i = 0; i < 16; ++i) {
                const float ks = __bfloat162float(tA[s0 + i][d]);
                accW[i] = fmaf(at, ks, accW[i]);
                accM[i] = fmaf(bt, ks, accM[i]);
            }
        }
        const float btc = sb_[t], Gt = sG[t];
        float mrow[16];
#pragma unroll
        for (int i = 0; i < 16; ++i) {
            const int s = s0 + i;
            const float ratio = (s <= t) ? expf(Gt - sG[s]) : 0.0f;  // <= 1
            Wl[t][s] = __float2bfloat16((s < t) ? btc * ratio * accW[i] : 0.0f);
            mrow[i] = ratio * accM[i];
        }
        __hip_bfloat16* mp = Mmat + (chnk * CS + t) * CS + s0;
        *(uint4*)(mp)     = pack8_bf16(&mrow[0]);
        *(uint4*)(mp + 8) = pack8_bf16(&mrow[8]);
    }
    __syncthreads();

    // Ti = (I+W)^-1 via forward elimination
    {
        const int t = tid >> 2, j0 = (tid & 3) * 16;
#pragma unroll
        for (int i = 0; i < 16; ++i) Ti[t][j0 + i] = (t == j0 + i) ? 1.0f : 0.0f;
    }
    __syncthreads();
    for (int s = 0; s < CS - 1; ++s) {
        const int t = tid & 63, jq = tid >> 6;
        if (t > s) {
            const float wt = -__bfloat162float(Wl[t][s]);
            const int jlo = jq * 16;
            const int jhi = min(s, jlo + 15);
            for (int j = jlo; j <= jhi; ++j)
                Ti[t][j] = fmaf(wt, Ti[s][j], Ti[t][j]);
        }
        __syncthreads();
    }

    // write Tinv (bf16); load b*v into tB
    {
        const int t = tid >> 2, j0 = (tid & 3) * 16;
        float trow[16];
#pragma unroll
        for (int i = 0; i < 16; ++i) trow[i] = Ti[t][j0 + i];
        __hip_bfloat16* tp = Tinv + (chnk * CS + t) * CS + j0;
        *(uint4*)(tp)     = pack8_bf16(&trow[0]);
        *(uint4*)(tp + 8) = pack8_bf16(&trow[8]);
    }
    {
        const int r = tid >> 2, d0 = (tid & 3) * 32;
        const float br = sb_[r];
        const uint4* vp = (const uint4*)(vb + (row0 + r) * DDIM + h * DHEAD + d0);
#pragma unroll
        for (int i = 0; i < 4; ++i) {
            const uint4 vv = vp[i];
            const unsigned short* u = (const unsigned short*)&vv;
            float f[8];
#pragma unroll
            for (int j = 0; j < 8; ++j) f[j] = br * bfbits2f(u[j]);
            *(uint4*)&tB[r][d0 + i * 8] = pack8_bf16(f);
        }
    }
    __syncthreads();

    // dv0 = Ti @ (b*v) -> dvX (bf16)
    {
        const int t = tid >> 2, j0 = (tid & 3) * 32;
        float acc[32];
#pragma unroll
        for (int j = 0; j < 32; ++j) acc[j] = 0.0f;
        for (int s = 0; s < CS; ++s) {
            const float ti = Ti[t][s];
#pragma unroll
            for (int j = 0; j < 32; ++j)
                acc[j] = fmaf(ti, __bfloat162float(tB[s][j0 + j]), acc[j]);
        }
        __hip_bfloat16* dp = dvX + (chnk * CS + t) * DHEAD + j0;
#pragma unroll
        for (int i = 0; i < 4; ++i)
            *(uint4*)(dp + i * 8) = pack8_bf16(&acc[i * 8]);
    }
}

// --------- Phase B (sequential over chunks; 16 bh x 8 v-slices) --------------
#define GV 8
#define VB 16   // DHEAD / GV

__global__ __launch_bounds__(512) void chunk_seq(
    const __hip_bfloat16* __restrict__ kb, const float* __restrict__ S0in,
    const float* __restrict__ betab, const float* __restrict__ Gcum,
    const __hip_bfloat16* __restrict__ Tinv,
    __hip_bfloat16* __restrict__ dvX,          // in: dv0, out: dv
    __hip_bfloat16* __restrict__ Ssnap, float* __restrict__ Sout)
{
    const int bh = blockIdx.x >> 3;
    const int g  = blockIdx.x & 7;
    const int b = bh >> 3, h = bh & 7;
    const int tid = threadIdx.x;
    const int j0 = g * VB;

    __shared__ float Ss[128][VB + 1];
    __shared__ __align__(16) __hip_bfloat16 kl[64][136];
    __shared__ __align__(16) __hip_bfloat16 Til[64][72];
    __shared__ float Pl[64][VB + 1];
    __shared__ float dvl[64][VB + 1];
    __shared__ float sBl[64], sGl[64];

    // load initial state slice
    {
        const int kk = tid >> 2;
        const int jj = (tid & 3) * 4;
        const float4 sv = *(const float4*)(S0in + ((long)bh * 128 + kk) * 128 + j0 + jj);
        Ss[kk][jj + 0] = sv.x; Ss[kk][jj + 1] = sv.y;
        Ss[kk][jj + 2] = sv.z; Ss[kk][jj + 3] = sv.w;
    }

    // staging maps
    const int sr  = tid >> 3;          // row 0..63
    const int sd0 = (tid & 7) * 16;    // k d base
    const int ts0 = (tid & 7) * 8;     // Ti s base
    const int dj0 = (tid & 7) * 2;     // dv0 j base

    uint4 kra, krb, treg;
    unsigned int dreg = 0;
    float breg = 0.0f, greg = 0.0f;

#define STAGE_LOAD(c_) do {                                                       \
        const long row0_ = (long)b * TLEN + (long)(c_) * CS;                      \
        const long chnk_ = (long)bh * NC + (c_);                                  \
        const __hip_bfloat16* kp_ = kb + (row0_ + sr) * DDIM + h * DHEAD + sd0;   \
        kra = *(const uint4*)(kp_);                                               \
        krb = *(const uint4*)(kp_ + 8);                                           \
        treg = *(const uint4*)(Tinv + (chnk_ * CS + sr) * CS + ts0);              \
        dreg = *(const unsigned int*)(dvX + (chnk_ * CS + sr) * DHEAD + j0 + dj0);\
        if (tid < 64) {                                                           \
            breg = betab[(row0_ + tid) * HHEADS + h];                             \
            greg = Gcum[chnk_ * CS + tid];                                        \
        }                                                                         \
    } while (0)

#define STAGE_WRITE() do {                                                        \
        *(uint4*)&kl[sr][sd0]     = kra;                                          \
        *(uint4*)&kl[sr][sd0 + 8] = krb;                                          \
        *(uint4*)&Til[sr][ts0] = treg;                                            \
        dvl[sr][dj0]     = bfbits2f((unsigned short)(dreg & 0xffff));             \
        dvl[sr][dj0 + 1] = bfbits2f((unsigned short)(dreg >> 16));                \
        if (tid < 64) { sBl[tid] = breg; sGl[tid] = greg; }                       \
    } while (0)

    STAGE_LOAD(0);
    STAGE_WRITE();
    __syncthreads();

    for (int c = 0; c < NC; ++c) {
        const long chnk = (long)bh * NC + c;
        if (c + 1 < NC) STAGE_LOAD(c + 1);
        const float G63 = sGl[CS - 1];
        const float A63 = expf(G63);

        // step 1: P[t][j] = b_t exp(G_t) * sum_kk k[t][kk] * Ss[kk][j]
        {
            const int t = tid >> 3;
            const int jj = (tid & 7) * 2;
            float a0 = 0.0f, a1 = 0.0f;
            for (int kk = 0; kk < 128; ++kk) {
                const float kv = __bfloat162float(kl[t][kk]);
                a0 = fmaf(kv, Ss[kk][jj], a0);
                a1 = fmaf(kv, Ss[kk][jj + 1], a1);
            }
            const float bA = sBl[t] * expf(sGl[t]);
            Pl[t][jj] = bA * a0;
            Pl[t][jj + 1] = bA * a1;
        }
        // snapshot chunk-initial S (bf16)
        {
            const int kk = tid >> 2;
            const int jj = (tid & 3) * 4;
            union { unsigned short u[4]; uint2 w; } pk;
            pk.u[0] = bf16_bits(Ss[kk][jj + 0]);
            pk.u[1] = bf16_bits(Ss[kk][jj + 1]);
            pk.u[2] = bf16_bits(Ss[kk][jj + 2]);
            pk.u[3] = bf16_bits(Ss[kk][jj + 3]);
            *(uint2*)(Ssnap + (chnk * 128 + kk) * 128 + j0 + jj) = pk.w;
        }
        __syncthreads();

        // step 2: dv = dv0 - Til @ P ; write raw dv (bf16); keep scaled in LDS
        {
            const int t = tid >> 3;
            const int jj = (tid & 7) * 2;
            float a0 = dvl[t][jj], a1 = dvl[t][jj + 1];
            for (int s = 0; s < CS; ++s) {
                const float ti = __bfloat162float(Til[t][s]);
                a0 = fmaf(-ti, Pl[s][jj], a0);
                a1 = fmaf(-ti, Pl[s][jj + 1], a1);
            }
            union { unsigned short u[2]; unsigned int w; } pk;
            pk.u[0] = bf16_bits(a0);
            pk.u[1] = bf16_bits(a1);
            *(unsigned int*)(dvX + (chnk * CS + t) * DHEAD + j0 + jj) = pk.w;
            const float rK = expf(G63 - sGl[t]);   // <= 1
            dvl[t][jj] = rK * a0;
            dvl[t][jj + 1] = rK * a1;
        }
        __syncthreads();

        // step 3: Ss = A63*Ss + sum_t k[t][kk] * dvl[t][j]
        {
            const int kk = tid & 127;
            const int jq = tid >> 7;
            float a_[4] = {0.0f, 0.0f, 0.0f, 0.0f};
            for (int t = 0; t < CS; ++t) {
                const float kv = __bfloat162float(kl[t][kk]);
                a_[0] = fmaf(kv, dvl[t][jq * 4 + 0], a_[0]);
                a_[1] = fmaf(kv, dvl[t][jq * 4 + 1], a_[1]);
                a_[2] = fmaf(kv, dvl[t][jq * 4 + 2], a_[2]);
                a_[3] = fmaf(kv, dvl[t][jq * 4 + 3], a_[3]);
            }
#pragma unroll
            for (int i = 0; i < 4; ++i)
                Ss[kk][jq * 4 + i] = A63 * Ss[kk][jq * 4 + i] + a_[i];
        }
        __syncthreads();
        if (c + 1 < NC) {
            STAGE_WRITE();
            __syncthreads();
        }
    }

    // final state
    {
        const int kk = tid >> 2;
        const int jj = (tid & 3) * 4;
        float4 sv;
        sv.x = Ss[kk][jj + 0]; sv.y = Ss[kk][jj + 1];
        sv.z = Ss[kk][jj + 2]; sv.w = Ss[kk][jj + 3];
        *(float4*)(Sout + ((long)bh * 128 + kk) * 128 + j0 + jj) = sv;
    }
#undef STAGE_LOAD
#undef STAGE_WRITE
}

// --------- Phase C (parallel): o = exp(G_t)*(q_t @ Ssnap) + M @ dv -----------
__global__ __launch_bounds__(256) void chunk_out(
    const __hip_bfloat16* __restrict__ qb, const float* __restrict__ Gcum,
    const __hip_bfloat16* __restrict__ dvX, const __hip_bfloat16* __restrict__ Ssnap,
    const __hip_bfloat16* __restrict__ Mmat, __hip_bfloat16* __restrict__ ob)
{
    const int bh = blockIdx.x >> 5;
    const int c  = blockIdx.x & 31;
    const int b = bh >> 3, h = bh & 7;
    const int tid = threadIdx.x;
    const long row0 = (long)b * TLEN + (long)c * CS;
    const long chnk = (long)bh * NC + c;

    __shared__ __align__(16) __hip_bfloat16 Ssn[128][136];
    __shared__ __align__(16) __hip_bfloat16 dvq[64][136];   // dv, later q
    __shared__ __align__(16) __hip_bfloat16 Ml[64][72];

    {
        const int kk = tid >> 1;
        const int d0 = (tid & 1) * 64;
        const uint4* sp = (const uint4*)(Ssnap + (chnk * 128 + kk) * 128 + d0);
#pragma unroll
        for (int i = 0; i < 8; ++i)
            *(uint4*)&Ssn[kk][d0 + i * 8] = sp[i];
    }
    {
        const int t = tid >> 2;
        const int s0 = (tid & 3) * 32;
        const uint4* dp = (const uint4*)(dvX + (chnk * CS + t) * DHEAD + s0);
#pragma unroll
        for (int i = 0; i < 4; ++i)
            *(uint4*)&dvq[t][s0 + i * 8] = dp[i];
    }
    {
        const int t = tid >> 2;
        const int s0 = (tid & 3) * 16;
        const uint4* mp = (const uint4*)(Mmat + (chnk * CS + t) * CS + s0);
        *(uint4*)&Ml[t][s0]     = mp[0];
        *(uint4*)&Ml[t][s0 + 8] = mp[1];
    }
    __syncthreads();

    const int t = tid >> 2;
    const int j0l = (tid & 3) * 32;
    float acc[32];
#pragma unroll
    for (int j = 0; j < 32; ++j) acc[j] = 0.0f;

    // part 1: M @ dv
    for (int s = 0; s < CS; ++s) {
        const float m = __bfloat162float(Ml[t][s]);
#pragma unroll
        for (int j = 0; j < 32; ++j)
            acc[j] = fmaf(m, __bfloat162float(dvq[s][j0l + j]), acc[j]);
    }
    __syncthreads();

    // load q chunk into dvq
    {
        const int r = tid >> 2, d0 = (tid & 3) * 32;
        const uint4* qp = (const uint4*)(qb + (row0 + r) * DDIM + h * DHEAD + d0);
#pragma unroll
        for (int i = 0; i < 4; ++i)
            *(uint4*)&dvq[r][d0 + i * 8] = qp[i];
    }
    __syncthreads();

    // part 2: + exp(G_t) * (q_t @ Ssnap)
    const float At = expf(Gcum[chnk * CS + t]);
    for (int kk = 0; kk < 128; ++kk) {
        const float qv = At * __bfloat162float(dvq[t][kk]);
#pragma unroll
        for (int j = 0; j < 32; ++j)
            acc[j] = fmaf(qv, __bfloat162float(Ssn[kk][j0l + j]), acc[j]);
    }

    __hip_bfloat16* op = ob + (row0 + t) * DDIM + h * DHEAD + j0l;
#pragma unroll
    for (int i = 0; i < 4; ++i)
        *(uint4*)(op + i * 8) = pack8_bf16(&acc[i * 8]);
}

extern "C" void kernel_launch(void* const* d_in, const int* in_sizes, int n_in,
                              void* d_out, int out_size, void* d_ws, size_t ws_size,
                              hipStream_t stream) {
    const float* x     = (const float*)d_in[0];
    const float* S0    = (const float*)d_in[1];
    const float* wq    = (const float*)d_in[2];
    const float* wk    = (const float*)d_in[3];
    const float* wv    = (const float*)d_in[4];
    const float* wb    = (const float*)d_in[5];
    const float* wg    = (const float*)d_in[6];
    const float* wo    = (const float*)d_in[7];
    const float* wgate = (const float*)d_in[8];
    const float* wup   = (const float*)d_in[9];
    const float* wdown = (const float*)d_in[10];

    const int M = BSZ * TLEN;  // 4096 token rows

    float* out  = (float*)d_out;
    float* Sout = out + (long)M * DDIM;

    // Workspace layout, peak 74.5 MiB (proven budget: 81 MiB from round 2).
    // Lifetimes carefully overlapped; see offsets.
    char* w = (char*)d_ws;
    const size_t MB = 1u << 20;
    const size_t KB = 1u << 10;
    __hip_bfloat16* qbh   = (__hip_bfloat16*)(w + 0 * MB);            // GEMM->C
    __hip_bfloat16* kbh   = (__hip_bfloat16*)(w + 8 * MB);            // GEMM->B
    __hip_bfloat16* vbh   = (__hip_bfloat16*)(w + 16 * MB);           // GEMM->A
    float*          beta  = (float*)(w + 24 * MB);                    // ->B
    float*          alpha = (float*)(w + 24 * MB + 128 * KB);         // ->A
    float*          Gcum  = (float*)(w + 24 * MB + 256 * KB);         // ->C
    __hip_bfloat16* Tinv  = (__hip_bfloat16*)(w + 24 * MB + 512 * KB);// A->B (4MB)
    __hip_bfloat16* Mmat  = (__hip_bfloat16*)(w + 28 * MB + 512 * KB);// A->C (4MB)
    __hip_bfloat16* dvX   = (__hip_bfloat16*)(w + 32 * MB + 512 * KB);// A->C (8MB)
    __hip_bfloat16* xnb   = (__hip_bfloat16*)(w + 32 * MB + 512 * KB);// rms1->QKV (dead before dvX)
    __hip_bfloat16* Ssnap = (__hip_bfloat16*)(w + 40 * MB + 512 * KB);// B->C (16MB)
    __hip_bfloat16* wqt   = (__hip_bfloat16*)(w + 40 * MB + 512 * KB);// ->QKV (dead before Ssnap)
    __hip_bfloat16* wkt   = (__hip_bfloat16*)(w + 42 * MB + 512 * KB);
    __hip_bfloat16* wvt   = (__hip_bfloat16*)(w + 44 * MB + 512 * KB);
    __hip_bfloat16* wot   = (__hip_bfloat16*)(w + 56 * MB + 512 * KB);// ->GEMM4 (2MB)
    __hip_bfloat16* wgt   = (__hip_bfloat16*)(w + 58 * MB + 512 * KB);// ->gateup (8MB)
    __hip_bfloat16* wut   = (__hip_bfloat16*)(w + 66 * MB + 512 * KB);// ->gateup (8MB)
    __hip_bfloat16* obufb = (__hip_bfloat16*)(w + 8 * MB);            // C->GEMM4 (kbh dead)
    __hip_bfloat16* xn2b  = (__hip_bfloat16*)(w + 8 * MB);            // rms2->gateup (obufb dead)
    __hip_bfloat16* wdt   = (__hip_bfloat16*)(w + 16 * MB);           // ->down (vbh dead)
    __hip_bfloat16* Hb    = (__hip_bfloat16*)(w + 24 * MB);           // gateup->down (32MB; scalars/Tinv/Mmat/dvX/Ssnap dead)

    // 0) weight transpose+convert (W[K,N] -> Wt[N,K] bf16)
    transpose_cvt<<<dim3(DDIM / 32, DDIM / 32), 256, 0, stream>>>(wq, wqt, DDIM, DDIM);
    transpose_cvt<<<dim3(DDIM / 32, DDIM / 32), 256, 0, stream>>>(wk, wkt, DDIM, DDIM);
    transpose_cvt<<<dim3(DDIM / 32, DDIM / 32), 256, 0, stream>>>(wv, wvt, DDIM, DDIM);
    transpose_cvt<<<dim3(DDIM / 32, DDIM / 32), 256, 0, stream>>>(wo, wot, DDIM, DDIM);
    transpose_cvt<<<dim3(FDIM / 32, DDIM / 32), 256, 0, stream>>>(wgate, wgt, DDIM, FDIM);
    transpose_cvt<<<dim3(FDIM / 32, DDIM / 32), 256, 0, stream>>>(wup, wut, DDIM, FDIM);

    // 1) norms / gates
    rmsnorm_k<<<M, 256, 0, stream>>>(x, xnb);
    ba_kernel<<<M, 64, 0, stream>>>(x, wb, wg, beta, alpha);

    // 2) q/k/v projections (bf16 out)
    dim3 gP(DDIM / 128, M / 128);
    gemm_bf16<2><<<gP, 256, 0, stream>>>(xnb, wqt, nullptr, qbh, M, DDIM, DDIM);
    gemm_bf16<2><<<gP, 256, 0, stream>>>(xnb, wkt, nullptr, kbh, M, DDIM, DDIM);
    gemm_bf16<2><<<gP, 256, 0, stream>>>(xnb, wvt, nullptr, vbh, M, DDIM, DDIM);
    postqkv<<<M * HHEADS, 64, 0, stream>>>(qbh, kbh, vbh);

    // 3) chunked delta rule
    chunk_prep<<<16 * NC, 256, 0, stream>>>(kbh, qbh, vbh, beta, alpha, Gcum, Tinv, dvX, Mmat);
    chunk_seq<<<16 * GV, 512, 0, stream>>>(kbh, S0, beta, Gcum, Tinv, dvX, Ssnap, Sout);
    chunk_out<<<16 * NC, 256, 0, stream>>>(qbh, Gcum, dvX, Ssnap, Mmat, obufb);

    // 4) x1 = x + o @ wo
    gemm_bf16<1><<<gP, 256, 0, stream>>>(obufb, wot, x, out, M, DDIM, DDIM);

    // 4b) transpose w_down into vbh slot (dead)
    transpose_cvt<<<dim3(DDIM / 32, FDIM / 32), 256, 0, stream>>>(wdown, wdt, FDIM, DDIM);

    // 5) xn2 = rms_norm(x1)
    rmsnorm_k<<<M, 256, 0, stream>>>(out, xn2b);

    // 6) H = silu(xn2 @ w_gate) * (xn2 @ w_up)
    dim3 gGU(FDIM / 128, M / 128);
    gemm_gateup_bf16<<<gGU, 256, 0, stream>>>(xn2b, wgt, wut, Hb, M, FDIM, DDIM);

    // 7) x_out = x1 + H @ w_down
    dim3 gDN(DDIM / 128, M / 128);
    gemm_bf16<1><<<gDN, 256, 0, stream>>>(Hb, wdt, out, out, M, DDIM, FDIM);
}